// Round 4
// baseline (634.847 us; speedup 1.0000x reference)
//
#include <hip/hip_runtime.h>

#define EPS 1e-5f
#define BSHIFT 9
#define BSIZE  512
#define NBMAX  256   // covers N up to 131072

__device__ __forceinline__ unsigned short f2bf(float f) {
    unsigned u = __float_as_uint(f);
    u += 0x7FFFu + ((u >> 16) & 1u);     // round-to-nearest-even
    return (unsigned short)(u >> 16);
}
__device__ __forceinline__ float bf2f(unsigned short s) {
    return __uint_as_float(((unsigned)s) << 16);
}

__global__ __launch_bounds__(256) void k_zero(unsigned* ghist, float* scal, int NB) {
    int t = threadIdx.x;
    if (t < NB) ghist[t] = 0u;
    if (t == 0) { scal[0] = 0.f; scal[1] = 0.f; }
}

// h[n][r] = sum_k x[n][k] * W[r][k], stored bf16. One node per thread; W in LDS (broadcast reads).
__global__ __launch_bounds__(256) void k_gemm(const float* __restrict__ x,
                                              const float* __restrict__ W,
                                              unsigned short* __restrict__ hbf, int N) {
    __shared__ float ws[16 * 256];       // W fp32, 16KB
    int t = threadIdx.x;
    for (int i = t; i < 1024; i += 256) ((float4*)ws)[i] = ((const float4*)W)[i];
    __syncthreads();
    int node = blockIdx.x * 256 + t;
    if (node >= N) return;
    const float4* xr = (const float4*)(x + (size_t)node * 256);
    float acc[16];
#pragma unroll
    for (int r = 0; r < 16; r++) acc[r] = 0.f;
#pragma unroll 4
    for (int k = 0; k < 64; k++) {
        float4 a = xr[k];
#pragma unroll
        for (int r = 0; r < 16; r++) {
            float4 w = ((const float4*)ws)[r * 64 + k];   // wave-broadcast LDS read
            acc[r] += a.x * w.x + a.y * w.y + a.z * w.z + a.w * w.w;
        }
    }
    unsigned pk[8];
#pragma unroll
    for (int i = 0; i < 8; i++)
        pk[i] = (unsigned)f2bf(acc[2 * i]) | ((unsigned)f2bf(acc[2 * i + 1]) << 16);
    uint4* dst = (uint4*)(hbf + (size_t)node * 16);
    dst[0] = make_uint4(pk[0], pk[1], pk[2], pk[3]);
    dst[1] = make_uint4(pk[4], pk[5], pk[6], pk[7]);
}

// bucket histogram: LDS-aggregated, ~NB global atomics per block (4096 edges/block)
__global__ __launch_bounds__(256) void k_bhist(const int* __restrict__ ei,
                                               unsigned* __restrict__ ghist, int E, int NB) {
    __shared__ unsigned sh[NBMAX];
    int t = threadIdx.x;
    for (int i = t; i < NB; i += 256) sh[i] = 0u;
    __syncthreads();
    const int4* dst4 = (const int4*)(ei + E);
    int E4 = E >> 2;
    int base4 = blockIdx.x * 1024;
#pragma unroll
    for (int i = 0; i < 4; i++) {
        int idx = base4 + i * 256 + t;
        if (idx < E4) {
            int4 d = dst4[idx];
            atomicAdd(&sh[d.x >> BSHIFT], 1u);
            atomicAdd(&sh[d.y >> BSHIFT], 1u);
            atomicAdd(&sh[d.z >> BSHIFT], 1u);
            atomicAdd(&sh[d.w >> BSHIFT], 1u);
        }
    }
    __syncthreads();
    for (int i = t; i < NB; i += 256) if (sh[i]) atomicAdd(&ghist[i], sh[i]);
}

// exclusive scan of ghist[NB] -> base, cursor; base[NB] = E
__global__ __launch_bounds__(256) void k_bscan(const unsigned* __restrict__ ghist,
                                               unsigned* __restrict__ base,
                                               unsigned* __restrict__ cursor, int NB, int E) {
    __shared__ unsigned sh[256];
    int t = threadIdx.x;
    unsigned v = (t < NB) ? ghist[t] : 0u;
    sh[t] = v;
    __syncthreads();
    for (int off = 1; off < 256; off <<= 1) {
        unsigned a = (t >= off) ? sh[t - off] : 0u;
        __syncthreads();
        sh[t] += a;
        __syncthreads();
    }
    if (t < NB) { unsigned ex = sh[t] - v; base[t] = ex; cursor[t] = ex; }
    if (t == 0) base[NB] = (unsigned)E;
}

// partition edges into bucket streams; packed u32 = src | (dst&511)<<17  (4096 edges/block)
__global__ __launch_bounds__(256) void k_bpart(const int* __restrict__ ei,
                                               unsigned* __restrict__ cursor,
                                               unsigned* __restrict__ sorted, int E, int NB) {
    __shared__ unsigned cnt[NBMAX];
    __shared__ unsigned lbase[NBMAX];
    int t = threadIdx.x;
    for (int i = t; i < NB; i += 256) cnt[i] = 0u;
    __syncthreads();
    const int4* src4 = (const int4*)ei;
    const int4* dst4 = (const int4*)(ei + E);
    int E4 = E >> 2;
    int base4 = blockIdx.x * 1024;
#pragma unroll
    for (int i = 0; i < 4; i++) {
        int idx = base4 + i * 256 + t;
        if (idx < E4) {
            int4 d = dst4[idx];
            atomicAdd(&cnt[d.x >> BSHIFT], 1u);
            atomicAdd(&cnt[d.y >> BSHIFT], 1u);
            atomicAdd(&cnt[d.z >> BSHIFT], 1u);
            atomicAdd(&cnt[d.w >> BSHIFT], 1u);
        }
    }
    __syncthreads();
    for (int i = t; i < NB; i += 256) {
        unsigned c = cnt[i];
        lbase[i] = c ? atomicAdd(&cursor[i], c) : 0u;
        cnt[i] = 0u;
    }
    __syncthreads();
#pragma unroll
    for (int i = 0; i < 4; i++) {
        int idx = base4 + i * 256 + t;
        if (idx < E4) {
            int4 s = src4[idx];
            int4 d = dst4[idx];
            {
                int b = d.x >> BSHIFT; unsigned off = atomicAdd(&cnt[b], 1u);
                sorted[lbase[b] + off] = (unsigned)s.x | ((unsigned)(d.x & (BSIZE - 1)) << 17);
            }
            {
                int b = d.y >> BSHIFT; unsigned off = atomicAdd(&cnt[b], 1u);
                sorted[lbase[b] + off] = (unsigned)s.y | ((unsigned)(d.y & (BSIZE - 1)) << 17);
            }
            {
                int b = d.z >> BSHIFT; unsigned off = atomicAdd(&cnt[b], 1u);
                sorted[lbase[b] + off] = (unsigned)s.z | ((unsigned)(d.z & (BSIZE - 1)) << 17);
            }
            {
                int b = d.w >> BSHIFT; unsigned off = atomicAdd(&cnt[b], 1u);
                sorted[lbase[b] + off] = (unsigned)s.w | ((unsigned)(d.w & (BSIZE - 1)) << 17);
            }
        }
    }
}

// per-bucket degree -> dinv = rsqrt(deg+1)
__global__ __launch_bounds__(256) void k_bdeg(const unsigned* __restrict__ base,
                                              const unsigned* __restrict__ sorted,
                                              float* __restrict__ dinv, int N) {
    __shared__ unsigned deg[BSIZE];
    int b = blockIdx.x, t = threadIdx.x;
    deg[t] = 0u; deg[t + 256] = 0u;
    __syncthreads();
    unsigned s0 = base[b], s1 = base[b + 1];
    for (unsigned j = s0 + t; j < s1; j += 256)
        atomicAdd(&deg[sorted[j] >> 17], 1u);
    __syncthreads();
    int n0 = b << BSHIFT;
    if (n0 + t < N)       dinv[n0 + t]       = rsqrtf((float)(deg[t] + 1u));
    if (n0 + 256 + t < N) dinv[n0 + 256 + t] = rsqrtf((float)(deg[t + 256] + 1u));
}

// channel-split LDS-tile aggregation: block (b,c) owns channels 4c..4c+3 of bucket b.
// 4-lane groups, one edge per group. Fused self-loop + LN stats on flush.
__global__ __launch_bounds__(512) void k_bagg(const unsigned* __restrict__ base,
                                              const unsigned* __restrict__ sorted,
                                              const unsigned short* __restrict__ hbf,
                                              const float* __restrict__ dinv,
                                              const float* __restrict__ bias,
                                              float* __restrict__ agg,
                                              float* __restrict__ scal, int N) {
    __shared__ float tile[BSIZE * 4];    // 8 KB
    int t = threadIdx.x;
    for (int i = t; i < BSIZE * 4; i += 512) tile[i] = 0.f;
    __syncthreads();
    int b = blockIdx.x >> 2, c = blockIdx.x & 3;
    int nbase = b << BSHIFT;
    unsigned s0 = base[b], s1 = base[b + 1];
    int G = t >> 2, q = t & 3;           // 128 groups of 4 lanes
    int ch = c * 4 + q;
    for (unsigned j = s0 + G; j < s1; j += 128) {
        unsigned u = sorted[j];          // 4-lane broadcast; wave reads 64B contiguous
        int src = (int)(u & 0x1FFFFu);
        int dlo = (int)(u >> 17);
        float v = bf2f(hbf[(size_t)src * 16 + ch]);
        float cf = dinv[src] * dinv[nbase + dlo];
        atomicAdd(&tile[dlo * 4 + q], v * cf);
    }
    __syncthreads();
    float s = 0.f, qs = 0.f;
    int node = nbase + t;
    if (node < N) {
        float dd = dinv[node];
        float sc = dd * dd;
        float4 tv = *(float4*)&tile[t * 4];
        const unsigned short* hn = hbf + (size_t)node * 16 + c * 4;
        float o0 = tv.x + bf2f(hn[0]) * sc;
        float o1 = tv.y + bf2f(hn[1]) * sc;
        float o2 = tv.z + bf2f(hn[2]) * sc;
        float o3 = tv.w + bf2f(hn[3]) * sc;
        *(float4*)(agg + (size_t)node * 16 + c * 4) = make_float4(o0, o1, o2, o3);
        float4 bv = ((const float4*)bias)[c];
        float a0 = o0 + bv.x, a1 = o1 + bv.y, a2 = o2 + bv.z, a3 = o3 + bv.w;
        s  = a0 + a1 + a2 + a3;
        qs = a0 * a0 + a1 * a1 + a2 * a2 + a3 * a3;
    }
    for (int off = 32; off > 0; off >>= 1) {
        s  += __shfl_down(s, off, 64);
        qs += __shfl_down(qs, off, 64);
    }
    __shared__ float ss[8], qq[8];
    int lane = t & 63, wid = t >> 6;
    if (lane == 0) { ss[wid] = s; qq[wid] = qs; }
    __syncthreads();
    if (t == 0) {
        float S = 0.f, Q = 0.f;
        for (int w = 0; w < 8; w++) { S += ss[w]; Q += qq[w]; }
        atomicAdd(&scal[0], S);
        atomicAdd(&scal[1], Q);
    }
}

// per batch row: LN + PReLU on 16 channels, then x trans[16,128] -> out[B,128]
__global__ __launch_bounds__(256) void k_final(const float* __restrict__ agg,
                                               const int* __restrict__ batch,
                                               const float* __restrict__ trans,
                                               const float* __restrict__ bias,
                                               const float* __restrict__ ln_w,
                                               const float* __restrict__ ln_b,
                                               const float* __restrict__ prelu_a,
                                               const float* __restrict__ scal,
                                               float* __restrict__ out, int B, float invCnt) {
    __shared__ float tl[16 * 128];
    __shared__ float hh[2 * 16];
    const int tid = threadIdx.x;
    for (int i = tid; i < 2048; i += 256) tl[i] = trans[i];
    float mean = scal[0] * invCnt;
    float var  = scal[1] * invCnt - mean * mean;
    float inv  = rsqrtf(var + EPS);
    int row0 = blockIdx.x * 2;
    if (tid < 32) {
        int lr = tid >> 4, r = tid & 15;
        int row = row0 + lr;
        if (row < B) {
            int node = batch[row];
            float v = agg[(size_t)node * 16 + r] + bias[r];
            v = (v - mean) * inv * ln_w[r] + ln_b[r];
            float a = prelu_a[0];
            v = v >= 0.f ? v : a * v;
            hh[lr * 16 + r] = v;
        }
    }
    __syncthreads();
    int lr = tid >> 7, d = tid & 127;
    int row = row0 + lr;
    if (row >= B) return;
    const float* hrow = hh + lr * 16;
    float acc = 0.f;
#pragma unroll
    for (int r = 0; r < 16; r++) acc += hrow[r] * tl[r * 128 + d];
    out[(size_t)row * 128 + d] = acc;
}

extern "C" void kernel_launch(void* const* d_in, const int* in_sizes, int n_in,
                              void* d_out, int out_size, void* d_ws, size_t ws_size,
                              hipStream_t stream) {
    const float* x       = (const float*)d_in[0];
    const int*   ei      = (const int*)d_in[1];
    const float* trans   = (const float*)d_in[2];
    const int*   batch   = (const int*)d_in[3];
    const float* W       = (const float*)d_in[4];
    const float* bias    = (const float*)d_in[5];
    const float* ln_w    = (const float*)d_in[6];
    const float* ln_b    = (const float*)d_in[7];
    const float* prelu_a = (const float*)d_in[8];
    float* out = (float*)d_out;

    const int N = in_sizes[0] / 256;   // 100000
    const int E = in_sizes[1] / 2;     // 3200000
    const int B = in_sizes[3];         // 16384
    const int NB = (N + BSIZE - 1) >> BSHIFT;   // 196

    char* p = (char*)d_ws;
    unsigned short* hbf = (unsigned short*)p;  p += (size_t)N * 16 * 2;   // 3.2MB bf16
    float*    agg    = (float*)p;      p += (size_t)N * 16 * 4;           // 6.4MB
    unsigned* sorted = (unsigned*)p;   p += (size_t)E * 4;                // 12.8MB
    float*    dinv   = (float*)p;      p += (size_t)N * 4;
    unsigned* ghist  = (unsigned*)p;   p += NBMAX * 4;
    unsigned* base   = (unsigned*)p;   p += (NBMAX + 1) * 4;
    unsigned* cursor = (unsigned*)p;   p += NBMAX * 4;
    float*    scal   = (float*)p;      p += 2 * 4;

    int E4 = E >> 2;
    int pb = (E4 + 1023) / 1024;       // 4096 edges per block

    hipLaunchKernelGGL(k_zero,  dim3(1),               dim3(256), 0, stream, ghist, scal, NB);
    hipLaunchKernelGGL(k_gemm,  dim3((N + 255) / 256), dim3(256), 0, stream, x, W, hbf, N);
    hipLaunchKernelGGL(k_bhist, dim3(pb),              dim3(256), 0, stream, ei, ghist, E, NB);
    hipLaunchKernelGGL(k_bscan, dim3(1),               dim3(256), 0, stream, ghist, base, cursor, NB, E);
    hipLaunchKernelGGL(k_bpart, dim3(pb),              dim3(256), 0, stream, ei, cursor, sorted, E, NB);
    hipLaunchKernelGGL(k_bdeg,  dim3(NB),              dim3(256), 0, stream, base, sorted, dinv, N);
    hipLaunchKernelGGL(k_bagg,  dim3(NB * 4),          dim3(512), 0, stream, base, sorted, hbf, dinv, bias, agg, scal, N);
    hipLaunchKernelGGL(k_final, dim3((B + 1) / 2),     dim3(256), 0, stream, agg, batch, trans, bias,
                       ln_w, ln_b, prelu_a, scal, out, B, 1.0f / (float)(N * 16));
}

// Round 5
// 498.546 us; speedup vs baseline: 1.2734x; 1.2734x over previous
//
#include <hip/hip_runtime.h>

#define EPS 1e-5f
#define BSHIFT 8
#define BSIZE  256
#define NBMAX  512   // covers N up to 131072 with 256-node buckets

__device__ __forceinline__ unsigned short f2bf(float f) {
    unsigned u = __float_as_uint(f);
    u += 0x7FFFu + ((u >> 16) & 1u);     // round-to-nearest-even
    return (unsigned short)(u >> 16);
}
__device__ __forceinline__ float bf2f(unsigned short s) {
    return __uint_as_float(((unsigned)s) << 16);
}

__global__ __launch_bounds__(512) void k_zero(unsigned* ghist, float* scal, int NB) {
    int t = threadIdx.x;
    if (t < NB) ghist[t] = 0u;
    if (t == 0) { scal[0] = 0.f; scal[1] = 0.f; }
}

// bucket histogram: LDS-aggregated (4096 edges/block)
__global__ __launch_bounds__(256) void k_bhist(const int* __restrict__ ei,
                                               unsigned* __restrict__ ghist, int E, int NB) {
    __shared__ unsigned sh[NBMAX];
    int t = threadIdx.x;
    for (int i = t; i < NB; i += 256) sh[i] = 0u;
    __syncthreads();
    const int4* dst4 = (const int4*)(ei + E);
    int E4 = E >> 2;
    int base4 = blockIdx.x * 1024;
#pragma unroll
    for (int i = 0; i < 4; i++) {
        int idx = base4 + i * 256 + t;
        if (idx < E4) {
            int4 d = dst4[idx];
            atomicAdd(&sh[d.x >> BSHIFT], 1u);
            atomicAdd(&sh[d.y >> BSHIFT], 1u);
            atomicAdd(&sh[d.z >> BSHIFT], 1u);
            atomicAdd(&sh[d.w >> BSHIFT], 1u);
        }
    }
    __syncthreads();
    for (int i = t; i < NB; i += 256) if (sh[i]) atomicAdd(&ghist[i], sh[i]);
}

// exclusive scan of ghist[NB] (NB <= 512) -> base, cursor; sentinels
__global__ __launch_bounds__(512) void k_bscan(const unsigned* __restrict__ ghist,
                                               unsigned* __restrict__ base,
                                               unsigned* __restrict__ cursor,
                                               unsigned* __restrict__ nstart,
                                               int NB, int N, int E) {
    __shared__ unsigned sh[512];
    int t = threadIdx.x;
    unsigned v = (t < NB) ? ghist[t] : 0u;
    sh[t] = v;
    __syncthreads();
    for (int off = 1; off < 512; off <<= 1) {
        unsigned a = (t >= off) ? sh[t - off] : 0u;
        __syncthreads();
        sh[t] += a;
        __syncthreads();
    }
    if (t < NB) { unsigned ex = sh[t] - v; base[t] = ex; cursor[t] = ex; }
    if (t == 0) { base[NB] = (unsigned)E; nstart[N] = (unsigned)E; }
}

// partition edges into bucket streams; packed u32 = src | (dst&255)<<17
__global__ __launch_bounds__(256) void k_bpart(const int* __restrict__ ei,
                                               unsigned* __restrict__ cursor,
                                               unsigned* __restrict__ sorted, int E, int NB) {
    __shared__ unsigned cnt[NBMAX];
    __shared__ unsigned lbase[NBMAX];
    int t = threadIdx.x;
    for (int i = t; i < NB; i += 256) cnt[i] = 0u;
    __syncthreads();
    const int4* src4 = (const int4*)ei;
    const int4* dst4 = (const int4*)(ei + E);
    int E4 = E >> 2;
    int base4 = blockIdx.x * 1024;
#pragma unroll
    for (int i = 0; i < 4; i++) {
        int idx = base4 + i * 256 + t;
        if (idx < E4) {
            int4 d = dst4[idx];
            atomicAdd(&cnt[d.x >> BSHIFT], 1u);
            atomicAdd(&cnt[d.y >> BSHIFT], 1u);
            atomicAdd(&cnt[d.z >> BSHIFT], 1u);
            atomicAdd(&cnt[d.w >> BSHIFT], 1u);
        }
    }
    __syncthreads();
    for (int i = t; i < NB; i += 256) {
        unsigned c = cnt[i];
        lbase[i] = c ? atomicAdd(&cursor[i], c) : 0u;
        cnt[i] = 0u;
    }
    __syncthreads();
#pragma unroll
    for (int i = 0; i < 4; i++) {
        int idx = base4 + i * 256 + t;
        if (idx < E4) {
            int4 s = src4[idx];
            int4 d = dst4[idx];
            {
                int b = d.x >> BSHIFT; unsigned off = atomicAdd(&cnt[b], 1u);
                sorted[lbase[b] + off] = (unsigned)s.x | ((unsigned)(d.x & (BSIZE - 1)) << 17);
            }
            {
                int b = d.y >> BSHIFT; unsigned off = atomicAdd(&cnt[b], 1u);
                sorted[lbase[b] + off] = (unsigned)s.y | ((unsigned)(d.y & (BSIZE - 1)) << 17);
            }
            {
                int b = d.z >> BSHIFT; unsigned off = atomicAdd(&cnt[b], 1u);
                sorted[lbase[b] + off] = (unsigned)s.z | ((unsigned)(d.z & (BSIZE - 1)) << 17);
            }
            {
                int b = d.w >> BSHIFT; unsigned off = atomicAdd(&cnt[b], 1u);
                sorted[lbase[b] + off] = (unsigned)s.w | ((unsigned)(d.w & (BSIZE - 1)) << 17);
            }
        }
    }
}

// per-bucket degree count + block scan -> nstart (global CSR row starts) + dinv
__global__ __launch_bounds__(256) void k_bdeg2(const unsigned* __restrict__ base,
                                               const unsigned* __restrict__ sorted,
                                               unsigned* __restrict__ nstart,
                                               float* __restrict__ dinv, int N) {
    __shared__ unsigned deg[BSIZE];
    int b = blockIdx.x, t = threadIdx.x;
    deg[t] = 0u;
    __syncthreads();
    unsigned s0 = base[b], s1 = base[b + 1];
    for (unsigned j = s0 + t; j < s1; j += 256)
        atomicAdd(&deg[sorted[j] >> 17], 1u);
    __syncthreads();
    unsigned d0 = deg[t];
    int lane = t & 63, wid = t >> 6;
    unsigned inc = d0;
    for (int off = 1; off < 64; off <<= 1) {
        unsigned u = __shfl_up(inc, off, 64);
        if (lane >= off) inc += u;
    }
    __shared__ unsigned wsum[4];
    if (lane == 63) wsum[wid] = inc;
    __syncthreads();
    unsigned wbase = 0;
    for (int w = 0; w < wid; w++) wbase += wsum[w];
    unsigned excl = wbase + inc - d0;
    int node = (b << BSHIFT) + t;
    if (node < N) {
        nstart[node] = s0 + excl;
        dinv[node] = rsqrtf((float)(d0 + 1u));   // +1 = self-loop
    }
}

// per-bucket counting-sort placement -> sorted2[j] = src, dst-sorted CSR order
__global__ __launch_bounds__(256) void k_bsort(const unsigned* __restrict__ base,
                                               const unsigned* __restrict__ nstart,
                                               const unsigned* __restrict__ sorted,
                                               unsigned* __restrict__ sorted2, int N) {
    __shared__ unsigned cur[BSIZE];
    int b = blockIdx.x, t = threadIdx.x;
    int node = (b << BSHIFT) + t;
    cur[t] = (node < N) ? nstart[node] : 0u;
    __syncthreads();
    unsigned s0 = base[b], s1 = base[b + 1];
    for (unsigned j = s0 + t; j < s1; j += 256) {
        unsigned u = sorted[j];
        unsigned pos = atomicAdd(&cur[u >> 17], 1u);
        sorted2[pos] = u & 0x1FFFFu;
    }
}

// hs[n][r] = (sum_k x[n][k]*W[r][k]) * dinv[n], stored bf16.
__global__ __launch_bounds__(256) void k_gemm(const float* __restrict__ x,
                                              const float* __restrict__ W,
                                              const float* __restrict__ dinv,
                                              unsigned short* __restrict__ hs, int N) {
    __shared__ float ws[16 * 256];       // W fp32, 16KB
    int t = threadIdx.x;
    for (int i = t; i < 1024; i += 256) ((float4*)ws)[i] = ((const float4*)W)[i];
    __syncthreads();
    int node = blockIdx.x * 256 + t;
    if (node >= N) return;
    const float4* xr = (const float4*)(x + (size_t)node * 256);
    float acc[16];
#pragma unroll
    for (int r = 0; r < 16; r++) acc[r] = 0.f;
#pragma unroll 4
    for (int k = 0; k < 64; k++) {
        float4 a = xr[k];
#pragma unroll
        for (int r = 0; r < 16; r++) {
            float4 w = ((const float4*)ws)[r * 64 + k];   // wave-broadcast LDS read
            acc[r] += a.x * w.x + a.y * w.y + a.z * w.z + a.w * w.w;
        }
    }
    float dv = dinv[node];
    unsigned pk[8];
#pragma unroll
    for (int i = 0; i < 8; i++)
        pk[i] = (unsigned)f2bf(acc[2 * i] * dv) | ((unsigned)f2bf(acc[2 * i + 1] * dv) << 16);
    uint4* dst = (uint4*)(hs + (size_t)node * 16);
    dst[0] = make_uint4(pk[0], pk[1], pk[2], pk[3]);
    dst[1] = make_uint4(pk[4], pk[5], pk[6], pk[7]);
}

// pull aggregation: 16 lanes per node, register accumulate, no atomics.
// agg[d][r] = (sum_{src} hs[src][r] + hs[d][r]) * dinv[d]; fused LN stats.
__global__ __launch_bounds__(256) void k_agg(const unsigned* __restrict__ nstart,
                                             const unsigned* __restrict__ sorted2,
                                             const unsigned short* __restrict__ hs,
                                             const float* __restrict__ dinv,
                                             const float* __restrict__ bias,
                                             float* __restrict__ agg,
                                             float* __restrict__ scal, int N) {
    int t = threadIdx.x;
    int g = t >> 4, r = t & 15;
    int d = blockIdx.x * 16 + g;
    float sv = 0.f;
    if (d < N) {
        unsigned s0 = nstart[d], s1 = nstart[d + 1];
        float acc = 0.f;
        unsigned j = s0;
        for (; j + 4 <= s1; j += 4) {
            unsigned a = sorted2[j], b = sorted2[j + 1], c = sorted2[j + 2], e = sorted2[j + 3];
            float v0 = bf2f(hs[(size_t)a * 16 + r]);
            float v1 = bf2f(hs[(size_t)b * 16 + r]);
            float v2 = bf2f(hs[(size_t)c * 16 + r]);
            float v3 = bf2f(hs[(size_t)e * 16 + r]);
            acc += (v0 + v1) + (v2 + v3);
        }
        for (; j < s1; j++) acc += bf2f(hs[(size_t)sorted2[j] * 16 + r]);
        float o = (acc + bf2f(hs[(size_t)d * 16 + r])) * dinv[d];
        agg[(size_t)d * 16 + r] = o;
        sv = o + bias[r];
    }
    float s = sv, q = sv * sv;
    for (int off = 32; off > 0; off >>= 1) {
        s += __shfl_down(s, off, 64);
        q += __shfl_down(q, off, 64);
    }
    __shared__ float ss[4], qq[4];
    int lane = t & 63, wid = t >> 6;
    if (lane == 0) { ss[wid] = s; qq[wid] = q; }
    __syncthreads();
    if (t == 0) {
        atomicAdd(&scal[0], ss[0] + ss[1] + ss[2] + ss[3]);
        atomicAdd(&scal[1], qq[0] + qq[1] + qq[2] + qq[3]);
    }
}

// per batch row: LN + PReLU on 16 channels, then x trans[16,128] -> out[B,128]
__global__ __launch_bounds__(256) void k_final(const float* __restrict__ agg,
                                               const int* __restrict__ batch,
                                               const float* __restrict__ trans,
                                               const float* __restrict__ bias,
                                               const float* __restrict__ ln_w,
                                               const float* __restrict__ ln_b,
                                               const float* __restrict__ prelu_a,
                                               const float* __restrict__ scal,
                                               float* __restrict__ out, int B, float invCnt) {
    __shared__ float tl[16 * 128];
    __shared__ float hh[2 * 16];
    const int tid = threadIdx.x;
    for (int i = tid; i < 2048; i += 256) tl[i] = trans[i];
    float mean = scal[0] * invCnt;
    float var  = scal[1] * invCnt - mean * mean;
    float inv  = rsqrtf(var + EPS);
    int row0 = blockIdx.x * 2;
    if (tid < 32) {
        int lr = tid >> 4, r = tid & 15;
        int row = row0 + lr;
        if (row < B) {
            int node = batch[row];
            float v = agg[(size_t)node * 16 + r] + bias[r];
            v = (v - mean) * inv * ln_w[r] + ln_b[r];
            float a = prelu_a[0];
            v = v >= 0.f ? v : a * v;
            hh[lr * 16 + r] = v;
        }
    }
    __syncthreads();
    int lr = tid >> 7, d = tid & 127;
    int row = row0 + lr;
    if (row >= B) return;
    const float* hrow = hh + lr * 16;
    float acc = 0.f;
#pragma unroll
    for (int r = 0; r < 16; r++) acc += hrow[r] * tl[r * 128 + d];
    out[(size_t)row * 128 + d] = acc;
}

extern "C" void kernel_launch(void* const* d_in, const int* in_sizes, int n_in,
                              void* d_out, int out_size, void* d_ws, size_t ws_size,
                              hipStream_t stream) {
    const float* x       = (const float*)d_in[0];
    const int*   ei      = (const int*)d_in[1];
    const float* trans   = (const float*)d_in[2];
    const int*   batch   = (const int*)d_in[3];
    const float* W       = (const float*)d_in[4];
    const float* bias    = (const float*)d_in[5];
    const float* ln_w    = (const float*)d_in[6];
    const float* ln_b    = (const float*)d_in[7];
    const float* prelu_a = (const float*)d_in[8];
    float* out = (float*)d_out;

    const int N = in_sizes[0] / 256;   // 100000
    const int E = in_sizes[1] / 2;     // 3200000
    const int B = in_sizes[3];         // 16384
    const int NB = (N + BSIZE - 1) >> BSHIFT;   // 391

    char* p = (char*)d_ws;
    unsigned short* hs = (unsigned short*)p;  p += (size_t)N * 16 * 2;    // 3.2MB bf16
    float*    agg     = (float*)p;     p += (size_t)N * 16 * 4;           // 6.4MB
    unsigned* sorted  = (unsigned*)p;  p += (size_t)E * 4;                // 12.8MB
    unsigned* sorted2 = (unsigned*)p;  p += (size_t)E * 4;                // 12.8MB
    float*    dinv    = (float*)p;     p += (size_t)N * 4;
    unsigned* nstart  = (unsigned*)p;  p += (size_t)(N + 1) * 4;
    unsigned* ghist   = (unsigned*)p;  p += NBMAX * 4;
    unsigned* base    = (unsigned*)p;  p += (NBMAX + 1) * 4;
    unsigned* cursor  = (unsigned*)p;  p += NBMAX * 4;
    float*    scal    = (float*)p;     p += 2 * 4;

    int E4 = E >> 2;
    int pb = (E4 + 1023) / 1024;       // 4096 edges per block

    hipLaunchKernelGGL(k_zero,  dim3(1),               dim3(512), 0, stream, ghist, scal, NB);
    hipLaunchKernelGGL(k_bhist, dim3(pb),              dim3(256), 0, stream, ei, ghist, E, NB);
    hipLaunchKernelGGL(k_bscan, dim3(1),               dim3(512), 0, stream, ghist, base, cursor, nstart, NB, N, E);
    hipLaunchKernelGGL(k_bpart, dim3(pb),              dim3(256), 0, stream, ei, cursor, sorted, E, NB);
    hipLaunchKernelGGL(k_bdeg2, dim3(NB),              dim3(256), 0, stream, base, sorted, nstart, dinv, N);
    hipLaunchKernelGGL(k_bsort, dim3(NB),              dim3(256), 0, stream, base, nstart, sorted, sorted2, N);
    hipLaunchKernelGGL(k_gemm,  dim3((N + 255) / 256), dim3(256), 0, stream, x, W, dinv, hs, N);
    hipLaunchKernelGGL(k_agg,   dim3((N + 15) / 16),   dim3(256), 0, stream, nstart, sorted2, hs, dinv, bias, agg, scal, N);
    hipLaunchKernelGGL(k_final, dim3((B + 1) / 2),     dim3(256), 0, stream, agg, batch, trans, bias,
                       ln_w, ln_b, prelu_a, scal, out, B, 1.0f / (float)(N * 16));
}